// Round 12
// baseline (125.729 us; speedup 1.0000x reference)
//
#include <hip/hip_runtime.h>
#include <math.h>

// Problem constants: C=256, H=W=128, PH=PW=8.
#define C_ 256
#define H_ 128
#define W_ 128
#define PH_ 8
#define PW_ 8
#define HW_ (H_ * W_)

typedef unsigned short u16;
typedef u16 u16x4 __attribute__((ext_vector_type(4)));
typedef u16 u16x8 __attribute__((ext_vector_type(8)));

__device__ __forceinline__ u16x8 kmax(u16x8 a, u16x8 b) {
    return __builtin_elementwise_max(a, b);
}

// fp32 -> bf16 (RNE) -> monotone-mapped u16 key (unsigned order == float order)
__device__ __forceinline__ u16 f32_to_key(float f) {
    unsigned u = __float_as_uint(f);
    unsigned r = (u + 0x7fffu + ((u >> 16) & 1u)) >> 16;   // RNE to bf16
    u16 b = (u16)r;
    return (b & 0x8000u) ? (u16)~b : (u16)(b | 0x8000u);
}
__device__ __forceinline__ float key_to_f32(u16 k) {
    u16 b = (k & 0x8000u) ? (u16)(k & 0x7fffu) : (u16)~k;
    return __uint_as_float(((unsigned)b) << 16);
}

// ---------- Kernel 1: (C,H*W) fp32 -> blocked u16 keys + row-pair-max plane ----
// fmt:  (8 cg, H*W, 32ch)    full-res keys
// pmax: (8 cg, H/2*W, 32ch)  max over row pairs {2k, 2k+1}
__global__ __launch_bounds__(256) void transpose_kernel(
    const float* __restrict__ fm, u16* __restrict__ fmt, u16* __restrict__ pmax)
{
    __shared__ float tile[32 * 257];
    const int tid = threadIdx.x;
    const int g   = blockIdx.x & 7;
    const int hwb = blockIdx.x >> 3;
    const int c0  = g * 32;
    const int hw0 = hwb * 256;

    const int l    = tid & 63;
    const int crow = tid >> 6;
    const int sw   = (l >> 3) & 3;
    #pragma unroll
    for (int k = 0; k < 8; ++k) {
        const int c = crow + 4 * k;
        const float4 v = *(const float4*)(fm + (size_t)(c0 + c) * HW_ + hw0 + 4 * l);
        float* t = tile + c * 257 + 4 * l;
        t[(0 + sw) & 3] = v.x;
        t[(1 + sw) & 3] = v.y;
        t[(2 + sw) & 3] = v.z;
        t[(3 + sw) & 3] = v.w;
    }
    __syncthreads();

    u16* dst = fmt + (size_t)g * HW_ * 32;
    const int cq  = tid & 7;
    const int hwr = tid >> 3;
    #pragma unroll
    for (int m = 0; m < 8; ++m) {
        const int hw = hwr + 32 * m;
        const int o  = (hw & ~3) | (((hw & 3) + m) & 3);
        u16x4 w;
        w.x = f32_to_key(tile[(4 * cq + 0) * 257 + o]);
        w.y = f32_to_key(tile[(4 * cq + 1) * 257 + o]);
        w.z = f32_to_key(tile[(4 * cq + 2) * 257 + o]);
        w.w = f32_to_key(tile[(4 * cq + 3) * 257 + o]);
        *(u16x4*)(dst + (size_t)(hw0 + hw) * 32 + 4 * cq) = w;
    }

    // pair-max over rows h0=2*hwb (hw<128) and h0+1 (hw+128)
    u16* pdst = pmax + (size_t)g * (HW_ / 2) * 32;
    #pragma unroll
    for (int m = 0; m < 4; ++m) {
        const int w_ = hwr + 32 * m;                      // 0..127
        const int o  = (w_ & ~3) | (((w_ & 3) + m) & 3);
        u16x4 v;
        v.x = f32_to_key(fmaxf(tile[(4 * cq + 0) * 257 + o],
                               tile[(4 * cq + 0) * 257 + o + 128]));
        v.y = f32_to_key(fmaxf(tile[(4 * cq + 1) * 257 + o],
                               tile[(4 * cq + 1) * 257 + o + 128]));
        v.z = f32_to_key(fmaxf(tile[(4 * cq + 2) * 257 + o],
                               tile[(4 * cq + 2) * 257 + o + 128]));
        v.w = f32_to_key(fmaxf(tile[(4 * cq + 3) * 257 + o],
                               tile[(4 * cq + 3) * 257 + o + 128]));
        *(u16x4*)(pdst + ((size_t)hwb * W_ + w_) * 32 + 4 * cq) = v;
    }
}

// ---------- Kernel 2: pool, two ph bins software-pipelined per iteration ----
// Wave = (n, pw, cg); lane = 16 position-groups x 4 channel-octs. The column
// exec mask (col < we) is identical for all ph bins, so two bins' load
// bursts issue back-to-back before either is reduced -> bin A's vmcnt wait
// overlaps bin B's issue.
__global__ __launch_bounds__(256) void pool_kernel(
    const u16* __restrict__ fmt, const u16* __restrict__ pmax,
    const int* __restrict__ rois, float* __restrict__ out, int N)
{
    const int bid  = blockIdx.x;
    const int cg   = bid & 7;            // XCD-affine channel group
    const int r    = bid >> 3;
    const int half = r & 1;
    const int n    = r >> 1;

    const int wid  = threadIdx.x >> 6;
    const int lane = threadIdx.x & 63;
    const int pw   = half * 4 + wid;     // wave-uniform
    const int pg   = lane >> 2;          // position group 0..15
    const int co   = (lane & 3) << 3;    // channel offset: 0,8,16,24

    const int4 roi = ((const int4*)rois)[n];
    const int y = roi.x, x = roi.y, rH = roi.z, rW = roi.w;

    const int ws = (pw * rW) >> 3;
    const int we = ((pw + 1) * rW + 7) >> 3;
    const int bw = we - ws;              // 1..17

    const u16* plane  = fmt  + (size_t)cg * HW_ * 32;
    const u16* pplane = pmax + (size_t)cg * (HW_ / 2) * 32;
    const size_t RS = (size_t)W_ * 32;   // row stride in u16 (both arrays)

    const u16x8 z = {0, 0, 0, 0, 0, 0, 0, 0};

    if (bw <= 16) {
        const int col = ws + pg;
        const bool on = (col < we);
        const size_t cofs = (size_t)(x + col) * 32 + co;

        #pragma unroll 1
        for (int ph = 0; ph < PH_; ph += 2) {
            // ---- bin geometry (all wave-uniform) ----
            const int aA = y + ((ph * rH) >> 3);
            const int bA = y + (((ph + 1) * rH + 7) >> 3);
            const int k0A = (aA + 1) >> 1;
            const int npA = (bA >> 1) - k0A;
            const int lastA = npA - 1;

            const int aB = y + (((ph + 1) * rH) >> 3);
            const int bB = y + (((ph + 2) * rH + 7) >> 3);
            const int k0B = (aB + 1) >> 1;
            const int npB = (bB >> 1) - k0B;
            const int lastB = npB - 1;

            u16x8 tA0 = z, tA1 = z, tA2 = z, tA3 = z,
                  tA4 = z, tA5 = z, tA6 = z, tA7 = z, eA0 = z, eA1 = z;
            u16x8 tB0 = z, tB1 = z, tB2 = z, tB3 = z,
                  tB4 = z, tB5 = z, tB6 = z, tB7 = z, eB0 = z, eB1 = z;

            if (on) {
                // ---- bin A burst ----
                if (aA & 1) eA0 = *(const u16x8*)(plane + (size_t)aA * RS + cofs);
                if (bA & 1) eA1 = *(const u16x8*)(plane + (size_t)(bA - 1) * RS + cofs);
                if (npA > 0) {
                    const u16* pp = pplane + (size_t)k0A * RS + cofs;
                    tA0 = *(const u16x8*)(pp);
                    if (npA <= 4) {
                        tA1 = *(const u16x8*)(pp + (size_t)min(1, lastA) * RS);
                        tA2 = *(const u16x8*)(pp + (size_t)min(2, lastA) * RS);
                        tA3 = *(const u16x8*)(pp + (size_t)min(3, lastA) * RS);
                    } else {
                        tA1 = *(const u16x8*)(pp + RS);
                        tA2 = *(const u16x8*)(pp + 2 * RS);
                        tA3 = *(const u16x8*)(pp + 3 * RS);
                        tA4 = *(const u16x8*)(pp + 4 * RS);
                        tA5 = *(const u16x8*)(pp + (size_t)min(5, lastA) * RS);
                        tA6 = *(const u16x8*)(pp + (size_t)min(6, lastA) * RS);
                        tA7 = *(const u16x8*)(pp + (size_t)min(7, lastA) * RS);
                    }
                }
                // ---- bin B burst (issued before A is consumed) ----
                if (aB & 1) eB0 = *(const u16x8*)(plane + (size_t)aB * RS + cofs);
                if (bB & 1) eB1 = *(const u16x8*)(plane + (size_t)(bB - 1) * RS + cofs);
                if (npB > 0) {
                    const u16* pp = pplane + (size_t)k0B * RS + cofs;
                    tB0 = *(const u16x8*)(pp);
                    if (npB <= 4) {
                        tB1 = *(const u16x8*)(pp + (size_t)min(1, lastB) * RS);
                        tB2 = *(const u16x8*)(pp + (size_t)min(2, lastB) * RS);
                        tB3 = *(const u16x8*)(pp + (size_t)min(3, lastB) * RS);
                    } else {
                        tB1 = *(const u16x8*)(pp + RS);
                        tB2 = *(const u16x8*)(pp + 2 * RS);
                        tB3 = *(const u16x8*)(pp + 3 * RS);
                        tB4 = *(const u16x8*)(pp + 4 * RS);
                        tB5 = *(const u16x8*)(pp + (size_t)min(5, lastB) * RS);
                        tB6 = *(const u16x8*)(pp + (size_t)min(6, lastB) * RS);
                        tB7 = *(const u16x8*)(pp + (size_t)min(7, lastB) * RS);
                    }
                }
            }

            // ---- reduce bin A ----
            u16x8 accA = kmax(kmax(kmax(tA0, tA1), kmax(tA2, tA3)),
                              kmax(kmax(tA4, tA5), kmax(tA6, tA7)));
            accA = kmax(accA, kmax(eA0, eA1));
            // ---- reduce bin B ----
            u16x8 accB = kmax(kmax(kmax(tB0, tB1), kmax(tB2, tB3)),
                              kmax(kmax(tB4, tB5), kmax(tB6, tB7)));
            accB = kmax(accB, kmax(eB0, eB1));

            // cross-lane reduce over the 16 position groups (both bins)
            union U { u16x8 v; unsigned u[4]; };
            U ua, ub; ua.v = accA; ub.v = accB;
            #pragma unroll
            for (int mask = 4; mask <= 32; mask <<= 1) {
                U ta, tb;
                #pragma unroll
                for (int i = 0; i < 4; ++i) {
                    ta.u[i] = __shfl_xor(ua.u[i], mask, 64);
                    tb.u[i] = __shfl_xor(ub.u[i], mask, 64);
                }
                ua.v = __builtin_elementwise_max(ua.v, ta.v);
                ub.v = __builtin_elementwise_max(ub.v, tb.v);
            }

            if (pg == 0) {   // 4 lanes: each writes its 8 channels, both bins
                const int c = (cg << 5) + co;
                float* o = out + ((size_t)n * C_ + c) * (PH_ * PW_) + ph * PW_ + pw;
                #pragma unroll
                for (int i = 0; i < 8; ++i) {
                    o[(size_t)i * (PH_ * PW_)]       = key_to_f32(ua.v[i]);
                    o[(size_t)i * (PH_ * PW_) + PW_] = key_to_f32(ub.v[i]);
                }
            }
        }
    } else {
        // rare wide-bin path (bw == 17): R10's per-bin two-step loop
        const int nsteps = (bw + 15) >> 4;
        #pragma unroll 1
        for (int ph = 0; ph < PH_; ++ph) {
            const int a  = y + ((ph * rH) >> 3);
            const int b  = y + (((ph + 1) * rH + 7) >> 3);
            const int k0 = (a + 1) >> 1;
            const int np = (b >> 1) - k0;
            const int last = np - 1;

            u16x8 acc = z;
            for (int s = 0; s < nsteps; ++s) {
                const int col = ws + 16 * s + pg;
                if (col < we) {
                    const size_t cofs = (size_t)(x + col) * 32 + co;
                    if (a & 1)
                        acc = kmax(acc, *(const u16x8*)(plane + (size_t)a * RS + cofs));
                    if (b & 1)
                        acc = kmax(acc, *(const u16x8*)(plane + (size_t)(b - 1) * RS + cofs));
                    if (np > 0) {
                        const u16* pp = pplane + (size_t)k0 * RS + cofs;
                        u16x8 t0 = *(const u16x8*)(pp);
                        u16x8 t1 = *(const u16x8*)(pp + (size_t)min(1, last) * RS);
                        u16x8 t2 = *(const u16x8*)(pp + (size_t)min(2, last) * RS);
                        u16x8 t3 = *(const u16x8*)(pp + (size_t)min(3, last) * RS);
                        u16x8 t4 = *(const u16x8*)(pp + (size_t)min(4, last) * RS);
                        u16x8 t5 = *(const u16x8*)(pp + (size_t)min(5, last) * RS);
                        u16x8 t6 = *(const u16x8*)(pp + (size_t)min(6, last) * RS);
                        u16x8 t7 = *(const u16x8*)(pp + (size_t)min(7, last) * RS);
                        t0 = kmax(t0, t1); t2 = kmax(t2, t3);
                        t4 = kmax(t4, t5); t6 = kmax(t6, t7);
                        acc = kmax(acc, kmax(kmax(t0, t2), kmax(t4, t6)));
                    }
                }
            }

            union U { u16x8 v; unsigned u[4]; };
            U aa; aa.v = acc;
            #pragma unroll
            for (int mask = 4; mask <= 32; mask <<= 1) {
                U t;
                #pragma unroll
                for (int i = 0; i < 4; ++i) t.u[i] = __shfl_xor(aa.u[i], mask, 64);
                aa.v = __builtin_elementwise_max(aa.v, t.v);
            }

            if (pg == 0) {
                const int c = (cg << 5) + co;
                float* o = out + ((size_t)n * C_ + c) * (PH_ * PW_) + ph * PW_ + pw;
                #pragma unroll
                for (int i = 0; i < 8; ++i)
                    o[(size_t)i * (PH_ * PW_)] = key_to_f32(aa.v[i]);
            }
        }
    }
}

// ---------- Fallback if ws is too small ----------
__global__ __launch_bounds__(256) void roi_pool_fallback(
    const float* __restrict__ fm, const int* __restrict__ rois,
    float* __restrict__ out, int N)
{
    const int wid  = threadIdx.x >> 6;
    const int lane = threadIdx.x & 63;
    const int bid  = blockIdx.x;
    const int xcd  = bid & 7;
    const int t    = bid >> 3;
    const int csub = t & 7;
    const int n    = t >> 3;
    if (n >= N) return;
    const int c = (xcd << 5) + (csub << 2) + wid;

    const int4 roi = ((const int4*)rois)[n];
    const int y = roi.x, x = roi.y, rH = roi.z, rW = roi.w;

    const float2* plane2 = (const float2*)(fm + (size_t)c * (H_ * W_));
    const int pw = lane & 7;
    const int j  = lane >> 3;
    const int ws = (pw * rW) >> 3;
    const int we = (((pw + 1) * rW) + 7) >> 3;

    #pragma unroll
    for (int ph = 0; ph < PH_; ++ph) {
        const int hs = (ph * rH) >> 3;
        const int he = ((ph + 1) * rH + 7) >> 3;
        const float2* p = plane2 + (size_t)(y + hs) * (W_ / 2) + lane;
        float m0 = -INFINITY, m1 = -INFINITY;
        int cnt = he - hs;
        while (cnt >= 2) {
            const float2 a = p[0];
            const float2 b = p[W_ / 2];
            p += W_; cnt -= 2;
            m0 = fmaxf(m0, fmaxf(a.x, b.x));
            m1 = fmaxf(m1, fmaxf(a.y, b.y));
        }
        if (cnt) { const float2 a = p[0]; m0 = fmaxf(m0, a.x); m1 = fmaxf(m1, a.y); }

        float rr = -INFINITY;
        #pragma unroll
        for (int k = 0; k < 3; ++k) {
            const int w  = ws + j + k * 8;
            const int wa = x + w;
            const float a = __shfl(m0, (wa >> 1) & 63, 64);
            const float b = __shfl(m1, (wa >> 1) & 63, 64);
            if (w < we) rr = fmaxf(rr, (wa & 1) ? b : a);
        }
        rr = fmaxf(rr, __shfl_xor(rr, 8, 64));
        rr = fmaxf(rr, __shfl_xor(rr, 16, 64));
        rr = fmaxf(rr, __shfl_xor(rr, 32, 64));
        if (lane < PW_) out[(((size_t)n * C_ + c) * PH_ + ph) * PW_ + lane] = rr;
    }
}

extern "C" void kernel_launch(void* const* d_in, const int* in_sizes, int n_in,
                              void* d_out, int out_size, void* d_ws, size_t ws_size,
                              hipStream_t stream) {
    const float* fm   = (const float*)d_in[0];
    const int*   rois = (const int*)d_in[1];
    float*       out  = (float*)d_out;
    const int N = in_sizes[1] / 4;

    const size_t fmt_bytes  = (size_t)HW_ * C_ * sizeof(u16);       // 8.39 MB
    const size_t pmax_bytes = (size_t)(HW_ / 2) * C_ * sizeof(u16); // 4.19 MB
    if (ws_size >= fmt_bytes + pmax_bytes) {
        u16* fmt = (u16*)d_ws;
        u16* pmx = (u16*)((char*)d_ws + fmt_bytes);
        transpose_kernel<<<dim3((HW_ / 256) * 8), 256, 0, stream>>>(fm, fmt, pmx);
        pool_kernel<<<dim3(N * 2 * 8), 256, 0, stream>>>(fmt, pmx, rois, out, N);
    } else {
        roi_pool_fallback<<<dim3(64 * N), 256, 0, stream>>>(fm, rois, out, N);
    }
}

// Round 13
// 118.886 us; speedup vs baseline: 1.0576x; 1.0576x over previous
//
#include <hip/hip_runtime.h>
#include <math.h>

// Problem constants: C=256, H=W=128, PH=PW=8.
#define C_ 256
#define H_ 128
#define W_ 128
#define PH_ 8
#define PW_ 8
#define HW_ (H_ * W_)

typedef unsigned short u16;
typedef u16 u16x4 __attribute__((ext_vector_type(4)));
typedef u16 u16x8 __attribute__((ext_vector_type(8)));

__device__ __forceinline__ u16x8 kmax(u16x8 a, u16x8 b) {
    return __builtin_elementwise_max(a, b);
}

// fp32 -> bf16 (RNE) -> monotone-mapped u16 key (unsigned order == float order)
__device__ __forceinline__ u16 f32_to_key(float f) {
    unsigned u = __float_as_uint(f);
    unsigned r = (u + 0x7fffu + ((u >> 16) & 1u)) >> 16;   // RNE to bf16
    u16 b = (u16)r;
    return (b & 0x8000u) ? (u16)~b : (u16)(b | 0x8000u);
}
__device__ __forceinline__ float key_to_f32(u16 k) {
    u16 b = (k & 0x8000u) ? (u16)(k & 0x7fffu) : (u16)~k;
    return __uint_as_float(((unsigned)b) << 16);
}

// ---------- Kernel 1: (C,H*W) fp32 -> blocked u16 keys + row-pair-max plane ----
// fmt:  (8 cg, H*W, 32ch)    full-res keys
// pmax: (8 cg, H/2*W, 32ch)  max over row pairs {2k, 2k+1}
__global__ __launch_bounds__(256) void transpose_kernel(
    const float* __restrict__ fm, u16* __restrict__ fmt, u16* __restrict__ pmax)
{
    __shared__ float tile[32 * 257];
    const int tid = threadIdx.x;
    const int g   = blockIdx.x & 7;
    const int hwb = blockIdx.x >> 3;
    const int c0  = g * 32;
    const int hw0 = hwb * 256;

    const int l    = tid & 63;
    const int crow = tid >> 6;
    const int sw   = (l >> 3) & 3;
    #pragma unroll
    for (int k = 0; k < 8; ++k) {
        const int c = crow + 4 * k;
        const float4 v = *(const float4*)(fm + (size_t)(c0 + c) * HW_ + hw0 + 4 * l);
        float* t = tile + c * 257 + 4 * l;
        t[(0 + sw) & 3] = v.x;
        t[(1 + sw) & 3] = v.y;
        t[(2 + sw) & 3] = v.z;
        t[(3 + sw) & 3] = v.w;
    }
    __syncthreads();

    u16* dst = fmt + (size_t)g * HW_ * 32;
    const int cq  = tid & 7;
    const int hwr = tid >> 3;
    #pragma unroll
    for (int m = 0; m < 8; ++m) {
        const int hw = hwr + 32 * m;
        const int o  = (hw & ~3) | (((hw & 3) + m) & 3);
        u16x4 w;
        w.x = f32_to_key(tile[(4 * cq + 0) * 257 + o]);
        w.y = f32_to_key(tile[(4 * cq + 1) * 257 + o]);
        w.z = f32_to_key(tile[(4 * cq + 2) * 257 + o]);
        w.w = f32_to_key(tile[(4 * cq + 3) * 257 + o]);
        *(u16x4*)(dst + (size_t)(hw0 + hw) * 32 + 4 * cq) = w;
    }

    // pair-max over rows h0=2*hwb (hw<128) and h0+1 (hw+128)
    u16* pdst = pmax + (size_t)g * (HW_ / 2) * 32;
    #pragma unroll
    for (int m = 0; m < 4; ++m) {
        const int w_ = hwr + 32 * m;                      // 0..127
        const int o  = (w_ & ~3) | (((w_ & 3) + m) & 3);
        u16x4 v;
        v.x = f32_to_key(fmaxf(tile[(4 * cq + 0) * 257 + o],
                               tile[(4 * cq + 0) * 257 + o + 128]));
        v.y = f32_to_key(fmaxf(tile[(4 * cq + 1) * 257 + o],
                               tile[(4 * cq + 1) * 257 + o + 128]));
        v.z = f32_to_key(fmaxf(tile[(4 * cq + 2) * 257 + o],
                               tile[(4 * cq + 2) * 257 + o + 128]));
        v.w = f32_to_key(fmaxf(tile[(4 * cq + 3) * 257 + o],
                               tile[(4 * cq + 3) * 257 + o + 128]));
        *(u16x4*)(pdst + ((size_t)hwb * W_ + w_) * 32 + 4 * cq) = v;
    }
}

// ---------- Kernel 2: pool on u16 keys via pair-max + edge rows ----------
// Wave = (n, pw, cg, ph-half): 4 ph bins per wave (R10 structure, 2x the
// waves for TLP/balance). Lane = 16 position-groups x 4 channel-octs.
// Per bin: one independent load burst (edges from fmt + clamped pair loads
// from pmax) -> single vmcnt wait region per bin.
__global__ __launch_bounds__(256) void pool_kernel(
    const u16* __restrict__ fmt, const u16* __restrict__ pmax,
    const int* __restrict__ rois, float* __restrict__ out, int N)
{
    const int bid  = blockIdx.x;
    const int cg   = bid & 7;            // XCD-affine channel group
    const int phh  = (bid >> 3) & 1;     // ph half: bins phh*4 .. phh*4+3
    const int half = (bid >> 4) & 1;     // pw half
    const int n    = bid >> 5;

    const int wid  = threadIdx.x >> 6;
    const int lane = threadIdx.x & 63;
    const int pw   = half * 4 + wid;     // wave-uniform
    const int pg   = lane >> 2;          // position group 0..15
    const int co   = (lane & 3) << 3;    // channel offset: 0,8,16,24

    const int4 roi = ((const int4*)rois)[n];
    const int y = roi.x, x = roi.y, rH = roi.z, rW = roi.w;

    const int ws = (pw * rW) >> 3;
    const int we = ((pw + 1) * rW + 7) >> 3;
    const int bw = we - ws;              // 1..17
    const int nsteps = (bw + 15) >> 4;   // 1 or 2 (wave-uniform)

    const u16* plane  = fmt  + (size_t)cg * HW_ * 32;
    const u16* pplane = pmax + (size_t)cg * (HW_ / 2) * 32;
    const size_t RS = (size_t)W_ * 32;   // row stride in u16 (both arrays)

    #pragma unroll
    for (int pj = 0; pj < 4; ++pj) {
        const int ph = phh * 4 + pj;
        const int hs = (ph * rH) >> 3;
        const int he = ((ph + 1) * rH + 7) >> 3;
        const int a  = y + hs;           // first row (absolute)
        const int b  = y + he;           // last row + 1 (absolute)
        const int k0 = (a + 1) >> 1;     // first full pair
        const int k1 = b >> 1;           // one past last full pair
        const int np = k1 - k0;          // 0..8, wave-uniform

        u16x8 acc = {0, 0, 0, 0, 0, 0, 0, 0};   // minimum key

        for (int s = 0; s < nsteps; ++s) {
            const int col = ws + 16 * s + pg;
            if (col < we) {              // exec-masked: no traffic if off
                const size_t cofs = (size_t)(x + col) * 32 + co;
                if (a & 1)
                    acc = kmax(acc, *(const u16x8*)(plane + (size_t)a * RS + cofs));
                if (b & 1)
                    acc = kmax(acc, *(const u16x8*)(plane + (size_t)(b - 1) * RS + cofs));
                if (np > 0) {
                    const u16* pp = pplane + (size_t)k0 * RS + cofs;
                    const int last = np - 1;
                    if (np <= 4) {
                        u16x8 t0 = *(const u16x8*)(pp);
                        u16x8 t1 = *(const u16x8*)(pp + (size_t)min(1, last) * RS);
                        u16x8 t2 = *(const u16x8*)(pp + (size_t)min(2, last) * RS);
                        u16x8 t3 = *(const u16x8*)(pp + (size_t)min(3, last) * RS);
                        acc = kmax(acc, kmax(kmax(t0, t1), kmax(t2, t3)));
                    } else {
                        u16x8 t0 = *(const u16x8*)(pp);
                        u16x8 t1 = *(const u16x8*)(pp + RS);
                        u16x8 t2 = *(const u16x8*)(pp + 2 * RS);
                        u16x8 t3 = *(const u16x8*)(pp + 3 * RS);
                        u16x8 t4 = *(const u16x8*)(pp + 4 * RS);
                        u16x8 t5 = *(const u16x8*)(pp + (size_t)min(5, last) * RS);
                        u16x8 t6 = *(const u16x8*)(pp + (size_t)min(6, last) * RS);
                        u16x8 t7 = *(const u16x8*)(pp + (size_t)min(7, last) * RS);
                        t0 = kmax(t0, t1); t2 = kmax(t2, t3);
                        t4 = kmax(t4, t5); t6 = kmax(t6, t7);
                        acc = kmax(acc, kmax(kmax(t0, t2), kmax(t4, t6)));
                    }
                }
            }
        }

        // reduce across the 16 position groups (xor 4..32 on 4 dwords)
        union U { u16x8 v; unsigned u[4]; };
        U aa; aa.v = acc;
        #pragma unroll
        for (int mask = 4; mask <= 32; mask <<= 1) {
            U t;
            #pragma unroll
            for (int i = 0; i < 4; ++i) t.u[i] = __shfl_xor(aa.u[i], mask, 64);
            aa.v = __builtin_elementwise_max(aa.v, t.v);
        }

        if (pg == 0) {   // 4 lanes: each writes its 8 channels
            const int c = (cg << 5) + co;
            float* o = out + ((size_t)n * C_ + c) * (PH_ * PW_) + ph * PW_ + pw;
            #pragma unroll
            for (int i = 0; i < 8; ++i)
                o[(size_t)i * (PH_ * PW_)] = key_to_f32(aa.v[i]);
        }
    }
}

// ---------- Fallback if ws is too small ----------
__global__ __launch_bounds__(256) void roi_pool_fallback(
    const float* __restrict__ fm, const int* __restrict__ rois,
    float* __restrict__ out, int N)
{
    const int wid  = threadIdx.x >> 6;
    const int lane = threadIdx.x & 63;
    const int bid  = blockIdx.x;
    const int xcd  = bid & 7;
    const int t    = bid >> 3;
    const int csub = t & 7;
    const int n    = t >> 3;
    if (n >= N) return;
    const int c = (xcd << 5) + (csub << 2) + wid;

    const int4 roi = ((const int4*)rois)[n];
    const int y = roi.x, x = roi.y, rH = roi.z, rW = roi.w;

    const float2* plane2 = (const float2*)(fm + (size_t)c * (H_ * W_));
    const int pw = lane & 7;
    const int j  = lane >> 3;
    const int ws = (pw * rW) >> 3;
    const int we = (((pw + 1) * rW) + 7) >> 3;

    #pragma unroll
    for (int ph = 0; ph < PH_; ++ph) {
        const int hs = (ph * rH) >> 3;
        const int he = ((ph + 1) * rH + 7) >> 3;
        const float2* p = plane2 + (size_t)(y + hs) * (W_ / 2) + lane;
        float m0 = -INFINITY, m1 = -INFINITY;
        int cnt = he - hs;
        while (cnt >= 2) {
            const float2 a = p[0];
            const float2 b = p[W_ / 2];
            p += W_; cnt -= 2;
            m0 = fmaxf(m0, fmaxf(a.x, b.x));
            m1 = fmaxf(m1, fmaxf(a.y, b.y));
        }
        if (cnt) { const float2 a = p[0]; m0 = fmaxf(m0, a.x); m1 = fmaxf(m1, a.y); }

        float rr = -INFINITY;
        #pragma unroll
        for (int k = 0; k < 3; ++k) {
            const int w  = ws + j + k * 8;
            const int wa = x + w;
            const float a = __shfl(m0, (wa >> 1) & 63, 64);
            const float b = __shfl(m1, (wa >> 1) & 63, 64);
            if (w < we) rr = fmaxf(rr, (wa & 1) ? b : a);
        }
        rr = fmaxf(rr, __shfl_xor(rr, 8, 64));
        rr = fmaxf(rr, __shfl_xor(rr, 16, 64));
        rr = fmaxf(rr, __shfl_xor(rr, 32, 64));
        if (lane < PW_) out[(((size_t)n * C_ + c) * PH_ + ph) * PW_ + lane] = rr;
    }
}

extern "C" void kernel_launch(void* const* d_in, const int* in_sizes, int n_in,
                              void* d_out, int out_size, void* d_ws, size_t ws_size,
                              hipStream_t stream) {
    const float* fm   = (const float*)d_in[0];
    const int*   rois = (const int*)d_in[1];
    float*       out  = (float*)d_out;
    const int N = in_sizes[1] / 4;

    const size_t fmt_bytes  = (size_t)HW_ * C_ * sizeof(u16);       // 8.39 MB
    const size_t pmax_bytes = (size_t)(HW_ / 2) * C_ * sizeof(u16); // 4.19 MB
    if (ws_size >= fmt_bytes + pmax_bytes) {
        u16* fmt = (u16*)d_ws;
        u16* pmx = (u16*)((char*)d_ws + fmt_bytes);
        transpose_kernel<<<dim3((HW_ / 256) * 8), 256, 0, stream>>>(fm, fmt, pmx);
        pool_kernel<<<dim3(N * 32), 256, 0, stream>>>(fmt, pmx, rois, out, N);
    } else {
        roi_pool_fallback<<<dim3(64 * N), 256, 0, stream>>>(fm, rois, out, N);
    }
}

// Round 14
// 118.351 us; speedup vs baseline: 1.0623x; 1.0045x over previous
//
#include <hip/hip_runtime.h>
#include <math.h>

// Problem constants: C=256, H=W=128, PH=PW=8.
#define C_ 256
#define H_ 128
#define W_ 128
#define PH_ 8
#define PW_ 8
#define HW_ (H_ * W_)
#define M3ROWS (H_ - 8 + 1)   // 121 sliding-window rows

typedef unsigned short u16;
typedef u16 u16x4 __attribute__((ext_vector_type(4)));
typedef u16 u16x8 __attribute__((ext_vector_type(8)));

__device__ __forceinline__ u16x8 kmax(u16x8 a, u16x8 b) {
    return __builtin_elementwise_max(a, b);
}

// fp32 -> bf16 (RNE) -> monotone-mapped u16 key (unsigned order == float order)
__device__ __forceinline__ u16 f32_to_key(float f) {
    unsigned u = __float_as_uint(f);
    unsigned r = (u + 0x7fffu + ((u >> 16) & 1u)) >> 16;   // RNE to bf16
    u16 b = (u16)r;
    return (b & 0x8000u) ? (u16)~b : (u16)(b | 0x8000u);
}
__device__ __forceinline__ float key_to_f32(u16 k) {
    u16 b = (k & 0x8000u) ? (u16)(k & 0x7fffu) : (u16)~k;
    return __uint_as_float(((unsigned)b) << 16);
}

// ---------- Kernel 1: (C,H*W) fp32 -> blocked (8 cg, H*W, 32ch) u16 keys ----
__global__ __launch_bounds__(256) void transpose_kernel(
    const float* __restrict__ fm, u16* __restrict__ fmt)
{
    __shared__ float tile[32 * 257];
    const int tid = threadIdx.x;
    const int g   = blockIdx.x & 7;
    const int hwb = blockIdx.x >> 3;
    const int c0  = g * 32;
    const int hw0 = hwb * 256;

    const int l    = tid & 63;
    const int crow = tid >> 6;
    const int sw   = (l >> 3) & 3;
    #pragma unroll
    for (int k = 0; k < 8; ++k) {
        const int c = crow + 4 * k;
        const float4 v = *(const float4*)(fm + (size_t)(c0 + c) * HW_ + hw0 + 4 * l);
        float* t = tile + c * 257 + 4 * l;
        t[(0 + sw) & 3] = v.x;
        t[(1 + sw) & 3] = v.y;
        t[(2 + sw) & 3] = v.z;
        t[(3 + sw) & 3] = v.w;
    }
    __syncthreads();

    u16* dst = fmt + (size_t)g * HW_ * 32;
    const int cq  = tid & 7;
    const int hwr = tid >> 3;
    #pragma unroll
    for (int m = 0; m < 8; ++m) {
        const int hw = hwr + 32 * m;
        const int o  = (hw & ~3) | (((hw & 3) + m) & 3);
        u16x4 w;
        w.x = f32_to_key(tile[(4 * cq + 0) * 257 + o]);
        w.y = f32_to_key(tile[(4 * cq + 1) * 257 + o]);
        w.z = f32_to_key(tile[(4 * cq + 2) * 257 + o]);
        w.w = f32_to_key(tile[(4 * cq + 3) * 257 + o]);
        *(u16x4*)(dst + (size_t)(hw0 + hw) * 32 + 4 * cq) = w;
    }
}

// ---------- Kernel 2: sliding 8-row max  M3[i] = max(fmt rows [i, i+8)) ----
// 64 blocks = 8 cg x 8 h-bands (XCD-affine: bid&7 = cg). Thread = (w0, co),
// ring buffer of 8 u16x8 rows, fully unrolled (band start is 16-aligned so
// ring indices are compile-time).
__global__ __launch_bounds__(256) void m3_kernel(
    const u16* __restrict__ fmt, u16* __restrict__ m3)
{
    const int bid  = blockIdx.x;
    const int g    = bid & 7;
    const int band = bid >> 3;          // 0..7
    const int i0   = band * 16;
    const int t    = threadIdx.x;
    const int co   = (t & 3) << 3;
    const int w0   = t >> 2;            // 0..63

    const u16* src = fmt + (size_t)g * HW_ * 32;
    u16*       dst = m3  + (size_t)g * M3ROWS * (W_ * 32);
    const size_t RS = (size_t)W_ * 32;

    #pragma unroll 1
    for (int seg = 0; seg < 2; ++seg) {
        const int w = w0 + 64 * seg;
        const size_t cofs = (size_t)w * 32 + co;
        u16x8 r[8];
        #pragma unroll
        for (int k = 0; k < 7; ++k)
            r[k] = *(const u16x8*)(src + (size_t)(i0 + k) * RS + cofs);
        #pragma unroll
        for (int j = 0; j < 16; ++j) {
            const int i = i0 + j;
            if (i < M3ROWS) {
                r[(j + 7) & 7] = *(const u16x8*)(src + (size_t)(i + 7) * RS + cofs);
                u16x8 m01 = kmax(r[0], r[1]);
                u16x8 m23 = kmax(r[2], r[3]);
                u16x8 m45 = kmax(r[4], r[5]);
                u16x8 m67 = kmax(r[6], r[7]);
                *(u16x8*)(dst + (size_t)i * RS + cofs) =
                    kmax(kmax(m01, m23), kmax(m45, m67));
            }
        }
    }
}

// ---------- Kernel 3: pool via RMQ decomposition ----------
// Wave = (n, pw, cg, ph-half): 4 ph bins per wave (R12 structure).
// Lane = 16 position-groups x 4 channel-octs. Per bin (L = row count,
// wave-uniform): L>=8 -> 2 loads M3[a], M3[b-8] (+1 base iff L==17);
// L in 5..7 -> 7 clamped base loads; L<=4 -> 4 clamped base loads.
__global__ __launch_bounds__(256) void pool_kernel(
    const u16* __restrict__ fmt, const u16* __restrict__ m3,
    const int* __restrict__ rois, float* __restrict__ out, int N)
{
    const int bid  = blockIdx.x;
    const int cg   = bid & 7;            // XCD-affine channel group
    const int phh  = (bid >> 3) & 1;     // ph half
    const int half = (bid >> 4) & 1;     // pw half
    const int n    = bid >> 5;

    const int wid  = threadIdx.x >> 6;
    const int lane = threadIdx.x & 63;
    const int pw   = half * 4 + wid;     // wave-uniform
    const int pg   = lane >> 2;          // position group 0..15
    const int co   = (lane & 3) << 3;    // channel offset: 0,8,16,24

    const int4 roi = ((const int4*)rois)[n];
    const int y = roi.x, x = roi.y, rH = roi.z, rW = roi.w;

    const int ws = (pw * rW) >> 3;
    const int we = ((pw + 1) * rW + 7) >> 3;
    const int bw = we - ws;              // 1..17
    const int nsteps = (bw + 15) >> 4;   // 1 or 2 (wave-uniform)

    const u16* plane   = fmt + (size_t)cg * HW_ * 32;
    const u16* m3plane = m3  + (size_t)cg * M3ROWS * (W_ * 32);
    const size_t RS = (size_t)W_ * 32;   // row stride (both arrays)

    #pragma unroll
    for (int pj = 0; pj < 4; ++pj) {
        const int ph = phh * 4 + pj;
        const int hs = (ph * rH) >> 3;
        const int he = ((ph + 1) * rH + 7) >> 3;
        const int a  = y + hs;           // first row (absolute)
        const int b  = y + he;           // one past last row
        const int L  = he - hs;          // 1..17, wave-uniform

        u16x8 acc = {0, 0, 0, 0, 0, 0, 0, 0};   // minimum key

        for (int s = 0; s < nsteps; ++s) {
            const int col = ws + 16 * s + pg;
            if (col < we) {              // exec-masked: no traffic if off
                const size_t cofs = (size_t)(x + col) * 32 + co;
                if (L >= 8) {
                    u16x8 t0 = *(const u16x8*)(m3plane + (size_t)a * RS + cofs);
                    u16x8 t1 = *(const u16x8*)(m3plane + (size_t)(b - 8) * RS + cofs);
                    acc = kmax(acc, kmax(t0, t1));
                    if (L > 16)
                        acc = kmax(acc, *(const u16x8*)(plane + (size_t)(a + 8) * RS + cofs));
                } else if (L > 4) {      // 5..7 rows: 7 clamped base loads
                    const u16* pp = plane + (size_t)a * RS + cofs;
                    const int last = L - 1;
                    u16x8 t0 = *(const u16x8*)(pp);
                    u16x8 t1 = *(const u16x8*)(pp + RS);
                    u16x8 t2 = *(const u16x8*)(pp + 2 * RS);
                    u16x8 t3 = *(const u16x8*)(pp + 3 * RS);
                    u16x8 t4 = *(const u16x8*)(pp + 4 * RS);
                    u16x8 t5 = *(const u16x8*)(pp + (size_t)min(5, last) * RS);
                    u16x8 t6 = *(const u16x8*)(pp + (size_t)min(6, last) * RS);
                    acc = kmax(acc, kmax(kmax(kmax(t0, t1), kmax(t2, t3)),
                                         kmax(kmax(t4, t5), t6)));
                } else {                 // 1..4 rows: 4 clamped base loads
                    const u16* pp = plane + (size_t)a * RS + cofs;
                    const int last = L - 1;
                    u16x8 t0 = *(const u16x8*)(pp);
                    u16x8 t1 = *(const u16x8*)(pp + (size_t)min(1, last) * RS);
                    u16x8 t2 = *(const u16x8*)(pp + (size_t)min(2, last) * RS);
                    u16x8 t3 = *(const u16x8*)(pp + (size_t)min(3, last) * RS);
                    acc = kmax(acc, kmax(kmax(t0, t1), kmax(t2, t3)));
                }
            }
        }

        // reduce across the 16 position groups (xor 4..32 on 4 dwords)
        union U { u16x8 v; unsigned u[4]; };
        U aa; aa.v = acc;
        #pragma unroll
        for (int mask = 4; mask <= 32; mask <<= 1) {
            U t;
            #pragma unroll
            for (int i = 0; i < 4; ++i) t.u[i] = __shfl_xor(aa.u[i], mask, 64);
            aa.v = __builtin_elementwise_max(aa.v, t.v);
        }

        if (pg == 0) {   // 4 lanes: each writes its 8 channels
            const int c = (cg << 5) + co;
            float* o = out + ((size_t)n * C_ + c) * (PH_ * PW_) + ph * PW_ + pw;
            #pragma unroll
            for (int i = 0; i < 8; ++i)
                o[(size_t)i * (PH_ * PW_)] = key_to_f32(aa.v[i]);
        }
    }
}

// ---------- Fallback if ws is too small ----------
__global__ __launch_bounds__(256) void roi_pool_fallback(
    const float* __restrict__ fm, const int* __restrict__ rois,
    float* __restrict__ out, int N)
{
    const int wid  = threadIdx.x >> 6;
    const int lane = threadIdx.x & 63;
    const int bid  = blockIdx.x;
    const int xcd  = bid & 7;
    const int t    = bid >> 3;
    const int csub = t & 7;
    const int n    = t >> 3;
    if (n >= N) return;
    const int c = (xcd << 5) + (csub << 2) + wid;

    const int4 roi = ((const int4*)rois)[n];
    const int y = roi.x, x = roi.y, rH = roi.z, rW = roi.w;

    const float2* plane2 = (const float2*)(fm + (size_t)c * (H_ * W_));
    const int pw = lane & 7;
    const int j  = lane >> 3;
    const int ws = (pw * rW) >> 3;
    const int we = (((pw + 1) * rW) + 7) >> 3;

    #pragma unroll
    for (int ph = 0; ph < PH_; ++ph) {
        const int hs = (ph * rH) >> 3;
        const int he = ((ph + 1) * rH + 7) >> 3;
        const float2* p = plane2 + (size_t)(y + hs) * (W_ / 2) + lane;
        float m0 = -INFINITY, m1 = -INFINITY;
        int cnt = he - hs;
        while (cnt >= 2) {
            const float2 a = p[0];
            const float2 b = p[W_ / 2];
            p += W_; cnt -= 2;
            m0 = fmaxf(m0, fmaxf(a.x, b.x));
            m1 = fmaxf(m1, fmaxf(a.y, b.y));
        }
        if (cnt) { const float2 a = p[0]; m0 = fmaxf(m0, a.x); m1 = fmaxf(m1, a.y); }

        float rr = -INFINITY;
        #pragma unroll
        for (int k = 0; k < 3; ++k) {
            const int w  = ws + j + k * 8;
            const int wa = x + w;
            const float a = __shfl(m0, (wa >> 1) & 63, 64);
            const float b = __shfl(m1, (wa >> 1) & 63, 64);
            if (w < we) rr = fmaxf(rr, (wa & 1) ? b : a);
        }
        rr = fmaxf(rr, __shfl_xor(rr, 8, 64));
        rr = fmaxf(rr, __shfl_xor(rr, 16, 64));
        rr = fmaxf(rr, __shfl_xor(rr, 32, 64));
        if (lane < PW_) out[(((size_t)n * C_ + c) * PH_ + ph) * PW_ + lane] = rr;
    }
}

extern "C" void kernel_launch(void* const* d_in, const int* in_sizes, int n_in,
                              void* d_out, int out_size, void* d_ws, size_t ws_size,
                              hipStream_t stream) {
    const float* fm   = (const float*)d_in[0];
    const int*   rois = (const int*)d_in[1];
    float*       out  = (float*)d_out;
    const int N = in_sizes[1] / 4;

    const size_t fmt_bytes = (size_t)HW_ * C_ * sizeof(u16);            // 8.39 MB
    const size_t m3_bytes  = (size_t)M3ROWS * W_ * C_ * sizeof(u16);    // 7.93 MB
    if (ws_size >= fmt_bytes + m3_bytes) {
        u16* fmt = (u16*)d_ws;
        u16* m3  = (u16*)((char*)d_ws + fmt_bytes);
        transpose_kernel<<<dim3((HW_ / 256) * 8), 256, 0, stream>>>(fm, fmt);
        m3_kernel<<<dim3(64), 256, 0, stream>>>(fmt, m3);
        pool_kernel<<<dim3(N * 32), 256, 0, stream>>>(fmt, m3, rois, out, N);
    } else {
        roi_pool_fallback<<<dim3(64 * N), 256, 0, stream>>>(fm, rois, out, N);
    }
}